// Round 1
// baseline (191.164 us; speedup 1.0000x reference)
//
#include <hip/hip_runtime.h>

#define D 128
#define CAP 32
#define EPT 8          // edges per thread in bucket blocks
#define NEG_SLOPE 0.01f

typedef float v4f __attribute__((ext_vector_type(4)));
typedef short short8 __attribute__((ext_vector_type(8)));

static __device__ __forceinline__ short f2bf(float f) {
    unsigned u = __float_as_uint(f);
    unsigned r = (u + 0x7fffu + ((u >> 16) & 1u)) >> 16;   // round-nearest-even
    return (short)r;
}
static __device__ __forceinline__ float bflo(unsigned u) { return __uint_as_float(u << 16); }
static __device__ __forceinline__ float bfhi(unsigned u) { return __uint_as_float(u & 0xffff0000u); }
static __device__ __forceinline__ unsigned packbf(float x, float y) {
    return (unsigned)(unsigned short)f2bf(x) | ((unsigned)(unsigned short)f2bf(y) << 16);
}

// -------- fused, block-specialized: bucket blocks + conv blocks ------------
// blocks [0, nbB)      : bucket fill, EPT edges/thread, packed 4-B entries
// blocks [nbB, ...)    : fp32->bf16 conversion stream (features + W), float4-wide
__global__ __launch_bounds__(256) void convbucket_kernel(const float* __restrict__ feat,
                                                         const float* __restrict__ W1,
                                                         const float* __restrict__ W2,
                                                         const int* __restrict__ tgt,
                                                         const int* __restrict__ nbr,
                                                         const float* __restrict__ vals,
                                                         unsigned* __restrict__ featbf,
                                                         short* __restrict__ Wbf,
                                                         int* __restrict__ deg,
                                                         unsigned* __restrict__ edata,
                                                         int4* __restrict__ ovf,
                                                         int* __restrict__ ovf_cnt,
                                                         int nQuads, int E, int nbB) {
    if ((int)blockIdx.x < nbB) {
        // ---- bucket specialist: entry = (nbr<<16) | bf16(val) ----
        int base = (blockIdx.x * 256 + threadIdx.x) * EPT;
#pragma unroll
        for (int k = 0; k < EPT; k++) {
            int e = base + k;
            if (e < E) {
                int t    = tgt[e];
                int slot = atomicAdd(&deg[t], 1);
                if (slot < CAP) {
                    unsigned ent = ((unsigned)nbr[e] << 16) |
                                   (unsigned)(unsigned short)f2bf(vals[e]);
                    edata[((unsigned)t << 5) + slot] = ent;
                } else {
                    int o = atomicAdd(ovf_cnt, 1);
                    int4 ov;
                    ov.x = t;
                    ov.y = nbr[e];
                    ov.z = __float_as_int(vals[e]);
                    ov.w = 0;
                    ovf[o] = ov;
                }
            }
        }
    } else {
        // ---- conv specialist: float4 in, 2x packed bf16 out ----
        int i = (blockIdx.x - nbB) * 256 + threadIdx.x;
        if (i < nQuads) {
            float4 f = ((const float4*)feat)[i];
            uint2 p;
            p.x = packbf(f.x, f.y);
            p.y = packbf(f.z, f.w);
            ((uint2*)featbf)[i] = p;
        }
        if (i < D * D) {
            Wbf[i]         = f2bf(W1[i]);
            Wbf[D * D + i] = f2bf(W2[i]);
        }
    }
}

// -------- fused gather + dual-GEMM + bias + leaky relu ---------------------
// One wave = one 16-node MFMA tile. Gather results land in a wave-private,
// XOR-swizzled LDS tile (same swizzle scheme as the proven sW staging); the
// MFMA phase reads A-fragments from LDS and W fragments straight from global
// (Wbf = 64 KB, L1/L2-hot). No __syncthreads anywhere: LDS regions are
// wave-private, X1/X2 never touch global memory.
__global__ __launch_bounds__(256) void gathergemm_kernel(const unsigned* __restrict__ featbf,
                                                         const unsigned* __restrict__ edata,
                                                         const int* __restrict__ deg,
                                                         const int4* __restrict__ ovf,
                                                         const int* __restrict__ ovf_cnt,
                                                         const short* __restrict__ Wbf,
                                                         const float* __restrict__ b1,
                                                         const float* __restrict__ b2,
                                                         float* __restrict__ out,
                                                         int nNodes) {
    // [wave][mat][16 rows * 64 dwords] = 32 KB
    __shared__ __align__(16) unsigned sX[4][2][1024];

    int tid  = threadIdx.x;
    int lane = tid & 63;
    int w    = tid >> 6;
    int tile = blockIdx.x * 4 + w;
    int m0   = tile * 16;
    if (m0 >= nNodes) return;

    int mrow = lane & 15;   // A: m index / B(W): n index / D: col index
    int quad = lane >> 4;   // A/B: k-group    / D: row-group

    // bias is wave-invariant per lane: hoist + issue early
    float bias[8];
#pragma unroll
    for (int ot = 0; ot < 8; ot++) {
        int o = ot * 16 + mrow;
        bias[ot] = b1[o] + b2[o];
    }

    // preload all 16 degrees of this tile (lanes 16..63 replicate)
    int degv = deg[min(m0 + mrow, nNodes - 1)];

    // ---- phase 1: gather 16 nodes into the wave-private LDS tile ----
    for (int n = 0; n < 16; n++) {
        int node = m0 + n;
        int d    = (node < nNodes) ? __shfl(degv, n) : 0;
        int dd   = d < CAP ? d : CAP;

        unsigned uf = featbf[(long)min(node, nNodes - 1) * (D / 2) + lane];  // own row, issued early

        float ax0 = 0.f, ay0 = 0.f, ax1 = 0.f, ay1 = 0.f;
        float ax2 = 0.f, ay2 = 0.f, ax3 = 0.f, ay3 = 0.f;

        {
            const unsigned* ep = edata + ((unsigned)node << 5);
            int dm1 = dd - 1;
            // uniform loop: always 8 independent row loads in flight.
            for (int j = 0; j < dd; j += 8) {
                unsigned p0 = ep[min(j + 0, dm1)];
                unsigned p1 = ep[min(j + 1, dm1)];
                unsigned p2 = ep[min(j + 2, dm1)];
                unsigned p3 = ep[min(j + 3, dm1)];
                unsigned p4 = ep[min(j + 4, dm1)];
                unsigned p5 = ep[min(j + 5, dm1)];
                unsigned p6 = ep[min(j + 6, dm1)];
                unsigned p7 = ep[min(j + 7, dm1)];
                unsigned u0 = featbf[(long)(p0 >> 16) * (D / 2) + lane];
                unsigned u1 = featbf[(long)(p1 >> 16) * (D / 2) + lane];
                unsigned u2 = featbf[(long)(p2 >> 16) * (D / 2) + lane];
                unsigned u3 = featbf[(long)(p3 >> 16) * (D / 2) + lane];
                unsigned u4 = featbf[(long)(p4 >> 16) * (D / 2) + lane];
                unsigned u5 = featbf[(long)(p5 >> 16) * (D / 2) + lane];
                unsigned u6 = featbf[(long)(p6 >> 16) * (D / 2) + lane];
                unsigned u7 = featbf[(long)(p7 >> 16) * (D / 2) + lane];
                float v0 = (j + 0 < dd) ? bflo(p0) : 0.0f;
                float v1 = (j + 1 < dd) ? bflo(p1) : 0.0f;
                float v2 = (j + 2 < dd) ? bflo(p2) : 0.0f;
                float v3 = (j + 3 < dd) ? bflo(p3) : 0.0f;
                float v4 = (j + 4 < dd) ? bflo(p4) : 0.0f;
                float v5 = (j + 5 < dd) ? bflo(p5) : 0.0f;
                float v6 = (j + 6 < dd) ? bflo(p6) : 0.0f;
                float v7 = (j + 7 < dd) ? bflo(p7) : 0.0f;
                ax0 += bflo(u0) * v0; ay0 += bfhi(u0) * v0;
                ax1 += bflo(u1) * v1; ay1 += bfhi(u1) * v1;
                ax2 += bflo(u2) * v2; ay2 += bfhi(u2) * v2;
                ax3 += bflo(u3) * v3; ay3 += bfhi(u3) * v3;
                ax0 += bflo(u4) * v4; ay0 += bfhi(u4) * v4;
                ax1 += bflo(u5) * v5; ay1 += bfhi(u5) * v5;
                ax2 += bflo(u6) * v6; ay2 += bfhi(u6) * v6;
                ax3 += bflo(u7) * v7; ay3 += bfhi(u7) * v7;
            }
        }

        if (d > CAP) {
            // overflow edges live in the compact list (L2-hot, tiny)
            int cnt = *ovf_cnt;
            for (int basek = 0; basek < cnt; basek += 64) {
                int k = basek + lane;
                int t = (k < cnt) ? ovf[k].x : -1;
                unsigned long long m = __ballot(t == node);
                while (m) {
                    int b = __ffsll((long long)m) - 1;
                    m &= m - 1;
                    int4  ov = ovf[basek + b];
                    float v  = __int_as_float(ov.z);
                    unsigned u = featbf[(long)ov.y * (D / 2) + lane];
                    ax0 += bflo(u) * v;
                    ay0 += bfhi(u) * v;
                }
            }
        }

        float accx = (ax0 + ax1) + (ax2 + ax3);
        float accy = (ay0 + ay1) + (ay2 + ay3);
        float fx = bflo(uf), fy = bfhi(uf);
        // XOR-swizzled store: chunk c (=lane>>2) of row n lands at c^n.
        int idx = n * 64 + (((lane >> 2) ^ n) << 2) + (lane & 3);
        sX[w][0][idx] = packbf(fx + accx, fy + accy);
        sX[w][1][idx] = packbf(fx * accx, fy * accy);
    }

    // ---- phase 2: dual GEMM on the tile (A from LDS, W from global) ----
    v4f acc[8];
#pragma unroll
    for (int ot = 0; ot < 8; ot++) acc[ot] = (v4f)(0.0f);

#pragma unroll
    for (int s = 0; s < 4; s++) {
        int ck = s * 4 + quad;          // original chunk id wanted
        int pp = ck ^ mrow;             // swizzled position
        short8 a1 = *(const short8*)(&sX[w][0][mrow * 64 + pp * 4]);
        short8 a2 = *(const short8*)(&sX[w][1][mrow * 64 + pp * 4]);
        const short* wp = Wbf + ck * 8;
#pragma unroll
        for (int ot = 0; ot < 8; ot++) {
            int row = ot * 16 + mrow;
            short8 w1 = *(const short8*)(wp + row * D);
            short8 w2 = *(const short8*)(wp + D * D + row * D);
            acc[ot] = __builtin_amdgcn_mfma_f32_16x16x32_bf16(a1, w1, acc[ot], 0, 0, 0);
            acc[ot] = __builtin_amdgcn_mfma_f32_16x16x32_bf16(a2, w2, acc[ot], 0, 0, 0);
        }
    }

#pragma unroll
    for (int ot = 0; ot < 8; ot++) {
        int o = ot * 16 + mrow;
#pragma unroll
        for (int r = 0; r < 4; r++) {
            int node = m0 + quad * 4 + r;
            if (node < nNodes) {
                float v = acc[ot][r] + bias[ot];
                out[(long)node * D + o] = (v >= 0.0f) ? v : NEG_SLOPE * v;
            }
        }
    }
}

extern "C" void kernel_launch(void* const* d_in, const int* in_sizes, int n_in,
                              void* d_out, int out_size, void* d_ws, size_t ws_size,
                              hipStream_t stream) {
    const float* feat = (const float*)d_in[0];
    const int*   tgt  = (const int*)d_in[1];
    const int*   nbr  = (const int*)d_in[2];
    const float* vals = (const float*)d_in[3];
    const float* W1   = (const float*)d_in[4];
    const float* b1   = (const float*)d_in[5];
    const float* W2   = (const float*)d_in[6];
    const float* b2   = (const float*)d_in[7];
    float*       out  = (float*)d_out;

    int E      = in_sizes[1];
    int nNodes = out_size / D;

    // ---- workspace layout ----
    int*      deg     = (int*)d_ws;                             // N (+4 incl ovf_cnt)
    int*      ovf_cnt = deg + nNodes;                           // 1 (inside memset range)
    int4*     ovf     = (int4*)(deg + nNodes + 4);              // E entries (16B-aligned)
    unsigned* edata   = (unsigned*)(ovf + E);                   // N*CAP u32
    short*    Wbf     = (short*)(edata + (long)nNodes * CAP);   // 2*D*D
    unsigned* featbf  = (unsigned*)(Wbf + 2 * D * D);           // N*D/2

    int nQuads = nNodes * (D / 4);
    int nbB    = (E + 256 * EPT - 1) / (256 * EPT);   // 306 bucket blocks
    int nbC    = (nQuads + 255) / 256;                // 6250 conv blocks

    hipMemsetAsync(deg, 0, (size_t)(nNodes + 4) * sizeof(int), stream);
    convbucket_kernel<<<nbB + nbC, 256, 0, stream>>>(feat, W1, W2, tgt, nbr, vals,
                                                     featbf, Wbf, deg, edata, ovf, ovf_cnt,
                                                     nQuads, E, nbB);

    int nTiles  = (nNodes + 15) / 16;                 // 3125
    int nBlocks = (nTiles + 3) / 4;                   // 782 blocks of 4 waves
    gathergemm_kernel<<<nBlocks, 256, 0, stream>>>(featbf, edata, deg, ovf, ovf_cnt,
                                                   Wbf, b1, b2, out, nNodes);
}

// Round 2
// 181.753 us; speedup vs baseline: 1.0518x; 1.0518x over previous
//
#include <hip/hip_runtime.h>

#define D 128
#define CAP 32
#define EPT 8          // edges per thread in bucket blocks
#define NEG_SLOPE 0.01f

typedef float v4f __attribute__((ext_vector_type(4)));
typedef short short8 __attribute__((ext_vector_type(8)));

static __device__ __forceinline__ short f2bf(float f) {
    unsigned u = __float_as_uint(f);
    unsigned r = (u + 0x7fffu + ((u >> 16) & 1u)) >> 16;   // round-nearest-even
    return (short)r;
}
static __device__ __forceinline__ float bflo(unsigned u) { return __uint_as_float(u << 16); }
static __device__ __forceinline__ float bfhi(unsigned u) { return __uint_as_float(u & 0xffff0000u); }
static __device__ __forceinline__ unsigned packbf(float x, float y) {
    return (unsigned)(unsigned short)f2bf(x) | ((unsigned)(unsigned short)f2bf(y) << 16);
}

// -------- fused, block-specialized: bucket blocks + conv blocks ------------
// blocks [0, nbB)      : bucket fill, EPT edges/thread, packed 4-B entries
// blocks [nbB, ...)    : fp32->bf16 conversion stream (features + W), float4-wide
__global__ __launch_bounds__(256) void convbucket_kernel(const float* __restrict__ feat,
                                                         const float* __restrict__ W1,
                                                         const float* __restrict__ W2,
                                                         const int* __restrict__ tgt,
                                                         const int* __restrict__ nbr,
                                                         const float* __restrict__ vals,
                                                         unsigned* __restrict__ featbf,
                                                         short* __restrict__ Wbf,
                                                         int* __restrict__ deg,
                                                         unsigned* __restrict__ edata,
                                                         int4* __restrict__ ovf,
                                                         int* __restrict__ ovf_cnt,
                                                         int nQuads, int E, int nbB) {
    if ((int)blockIdx.x < nbB) {
        // ---- bucket specialist: entry = (nbr<<16) | bf16(val) ----
        int base = (blockIdx.x * 256 + threadIdx.x) * EPT;
#pragma unroll
        for (int k = 0; k < EPT; k++) {
            int e = base + k;
            if (e < E) {
                int t    = tgt[e];
                int slot = atomicAdd(&deg[t], 1);
                if (slot < CAP) {
                    unsigned ent = ((unsigned)nbr[e] << 16) |
                                   (unsigned)(unsigned short)f2bf(vals[e]);
                    edata[((unsigned)t << 5) + slot] = ent;
                } else {
                    int o = atomicAdd(ovf_cnt, 1);
                    int4 ov;
                    ov.x = t;
                    ov.y = nbr[e];
                    ov.z = __float_as_int(vals[e]);
                    ov.w = 0;
                    ovf[o] = ov;
                }
            }
        }
    } else {
        // ---- conv specialist: float4 in, 2x packed bf16 out ----
        int i = (blockIdx.x - nbB) * 256 + threadIdx.x;
        if (i < nQuads) {
            float4 f = ((const float4*)feat)[i];
            uint2 p;
            p.x = packbf(f.x, f.y);
            p.y = packbf(f.z, f.w);
            ((uint2*)featbf)[i] = p;
        }
        if (i < D * D) {
            Wbf[i]         = f2bf(W1[i]);
            Wbf[D * D + i] = f2bf(W2[i]);
        }
    }
}

// -------- fused gather + dual-GEMM + bias + leaky relu ---------------------
// One BLOCK = one 16-node MFMA tile, 4 waves cooperating:
//   phase 1: each wave gathers 4 nodes into a block-shared XOR-swizzled LDS
//            tile (restores the 12500-gather-wave TLP of the split version)
//   phase 2: each wave computes 2 of the 8 output column-blocks (16 MFMAs),
//            A from LDS, W straight from global (64 KB, L1/L2-hot).
// X1/X2 never touch global memory; only one __syncthreads.
__global__ __launch_bounds__(256) void gathergemm_kernel(const unsigned* __restrict__ featbf,
                                                         const unsigned* __restrict__ edata,
                                                         const int* __restrict__ deg,
                                                         const int4* __restrict__ ovf,
                                                         const int* __restrict__ ovf_cnt,
                                                         const short* __restrict__ Wbf,
                                                         const float* __restrict__ b1,
                                                         const float* __restrict__ b2,
                                                         float* __restrict__ out,
                                                         int nNodes) {
    // [mat][16 rows * 64 dwords] = 8 KB (block-shared tile)
    __shared__ __align__(16) unsigned sX[2][1024];

    int tid  = threadIdx.x;
    int lane = tid & 63;
    int w    = tid >> 6;
    int m0   = blockIdx.x * 16;
    if (m0 >= nNodes) return;   // uniform across block

    int mrow = lane & 15;   // A: m index / B(W): n index / D: col index
    int quad = lane >> 4;   // A/B: k-group    / D: row-group

    // ---- phase 1: this wave gathers nodes m0 + 4w .. m0 + 4w+3 ----
    for (int k = 0; k < 4; k++) {
        int n    = w * 4 + k;
        int node = m0 + n;
        int d    = (node < nNodes) ? deg[node] : 0;
        int dd   = d < CAP ? d : CAP;

        unsigned uf = featbf[(long)min(node, nNodes - 1) * (D / 2) + lane];  // own row, issued early

        float ax0 = 0.f, ay0 = 0.f, ax1 = 0.f, ay1 = 0.f;
        float ax2 = 0.f, ay2 = 0.f, ax3 = 0.f, ay3 = 0.f;

        {
            const unsigned* ep = edata + ((unsigned)node << 5);
            int dm1 = dd - 1;
            // uniform loop: always 8 independent row loads in flight.
            for (int j = 0; j < dd; j += 8) {
                unsigned p0 = ep[min(j + 0, dm1)];
                unsigned p1 = ep[min(j + 1, dm1)];
                unsigned p2 = ep[min(j + 2, dm1)];
                unsigned p3 = ep[min(j + 3, dm1)];
                unsigned p4 = ep[min(j + 4, dm1)];
                unsigned p5 = ep[min(j + 5, dm1)];
                unsigned p6 = ep[min(j + 6, dm1)];
                unsigned p7 = ep[min(j + 7, dm1)];
                unsigned u0 = featbf[(long)(p0 >> 16) * (D / 2) + lane];
                unsigned u1 = featbf[(long)(p1 >> 16) * (D / 2) + lane];
                unsigned u2 = featbf[(long)(p2 >> 16) * (D / 2) + lane];
                unsigned u3 = featbf[(long)(p3 >> 16) * (D / 2) + lane];
                unsigned u4 = featbf[(long)(p4 >> 16) * (D / 2) + lane];
                unsigned u5 = featbf[(long)(p5 >> 16) * (D / 2) + lane];
                unsigned u6 = featbf[(long)(p6 >> 16) * (D / 2) + lane];
                unsigned u7 = featbf[(long)(p7 >> 16) * (D / 2) + lane];
                float v0 = (j + 0 < dd) ? bflo(p0) : 0.0f;
                float v1 = (j + 1 < dd) ? bflo(p1) : 0.0f;
                float v2 = (j + 2 < dd) ? bflo(p2) : 0.0f;
                float v3 = (j + 3 < dd) ? bflo(p3) : 0.0f;
                float v4 = (j + 4 < dd) ? bflo(p4) : 0.0f;
                float v5 = (j + 5 < dd) ? bflo(p5) : 0.0f;
                float v6 = (j + 6 < dd) ? bflo(p6) : 0.0f;
                float v7 = (j + 7 < dd) ? bflo(p7) : 0.0f;
                ax0 += bflo(u0) * v0; ay0 += bfhi(u0) * v0;
                ax1 += bflo(u1) * v1; ay1 += bfhi(u1) * v1;
                ax2 += bflo(u2) * v2; ay2 += bfhi(u2) * v2;
                ax3 += bflo(u3) * v3; ay3 += bfhi(u3) * v3;
                ax0 += bflo(u4) * v4; ay0 += bfhi(u4) * v4;
                ax1 += bflo(u5) * v5; ay1 += bfhi(u5) * v5;
                ax2 += bflo(u6) * v6; ay2 += bfhi(u6) * v6;
                ax3 += bflo(u7) * v7; ay3 += bfhi(u7) * v7;
            }
        }

        if (d > CAP) {
            // overflow edges live in the compact list (L2-hot, tiny)
            int cnt = *ovf_cnt;
            for (int basek = 0; basek < cnt; basek += 64) {
                int kk = basek + lane;
                int t  = (kk < cnt) ? ovf[kk].x : -1;
                unsigned long long m = __ballot(t == node);
                while (m) {
                    int b = __ffsll((long long)m) - 1;
                    m &= m - 1;
                    int4  ov = ovf[basek + b];
                    float v  = __int_as_float(ov.z);
                    unsigned u = featbf[(long)ov.y * (D / 2) + lane];
                    ax0 += bflo(u) * v;
                    ay0 += bfhi(u) * v;
                }
            }
        }

        float accx = (ax0 + ax1) + (ax2 + ax3);
        float accy = (ay0 + ay1) + (ay2 + ay3);
        float fx = bflo(uf), fy = bfhi(uf);
        // XOR-swizzled store: chunk c (=lane>>2) of row n lands at c^n.
        int idx = n * 64 + (((lane >> 2) ^ n) << 2) + (lane & 3);
        sX[0][idx] = packbf(fx + accx, fy + accy);
        sX[1][idx] = packbf(fx * accx, fy * accy);
    }

    __syncthreads();

    // ---- phase 2: this wave computes output col-blocks ot = 2w, 2w+1 ----
    int ot0 = w * 2;
    float bias[2];
#pragma unroll
    for (int j = 0; j < 2; j++) {
        int o = (ot0 + j) * 16 + mrow;
        bias[j] = b1[o] + b2[o];
    }

    v4f acc[2];
#pragma unroll
    for (int j = 0; j < 2; j++) acc[j] = (v4f)(0.0f);

#pragma unroll
    for (int s = 0; s < 4; s++) {
        int ck = s * 4 + quad;          // original chunk id wanted
        int pp = ck ^ mrow;             // swizzled position
        short8 a1 = *(const short8*)(&sX[0][mrow * 64 + pp * 4]);
        short8 a2 = *(const short8*)(&sX[1][mrow * 64 + pp * 4]);
        const short* wp = Wbf + ck * 8;
#pragma unroll
        for (int j = 0; j < 2; j++) {
            int row = (ot0 + j) * 16 + mrow;
            short8 w1 = *(const short8*)(wp + row * D);
            short8 w2 = *(const short8*)(wp + D * D + row * D);
            acc[j] = __builtin_amdgcn_mfma_f32_16x16x32_bf16(a1, w1, acc[j], 0, 0, 0);
            acc[j] = __builtin_amdgcn_mfma_f32_16x16x32_bf16(a2, w2, acc[j], 0, 0, 0);
        }
    }

#pragma unroll
    for (int j = 0; j < 2; j++) {
        int o = (ot0 + j) * 16 + mrow;
#pragma unroll
        for (int r = 0; r < 4; r++) {
            int node = m0 + quad * 4 + r;
            if (node < nNodes) {
                float v = acc[j][r] + bias[j];
                out[(long)node * D + o] = (v >= 0.0f) ? v : NEG_SLOPE * v;
            }
        }
    }
}

extern "C" void kernel_launch(void* const* d_in, const int* in_sizes, int n_in,
                              void* d_out, int out_size, void* d_ws, size_t ws_size,
                              hipStream_t stream) {
    const float* feat = (const float*)d_in[0];
    const int*   tgt  = (const int*)d_in[1];
    const int*   nbr  = (const int*)d_in[2];
    const float* vals = (const float*)d_in[3];
    const float* W1   = (const float*)d_in[4];
    const float* b1   = (const float*)d_in[5];
    const float* W2   = (const float*)d_in[6];
    const float* b2   = (const float*)d_in[7];
    float*       out  = (float*)d_out;

    int E      = in_sizes[1];
    int nNodes = out_size / D;

    // ---- workspace layout ----
    int*      deg     = (int*)d_ws;                             // N (+4 incl ovf_cnt)
    int*      ovf_cnt = deg + nNodes;                           // 1 (inside memset range)
    int4*     ovf     = (int4*)(deg + nNodes + 4);              // E entries (16B-aligned)
    unsigned* edata   = (unsigned*)(ovf + E);                   // N*CAP u32
    short*    Wbf     = (short*)(edata + (long)nNodes * CAP);   // 2*D*D
    unsigned* featbf  = (unsigned*)(Wbf + 2 * D * D);           // N*D/2

    int nQuads = nNodes * (D / 4);
    int nbB    = (E + 256 * EPT - 1) / (256 * EPT);   // 306 bucket blocks
    int nbC    = (nQuads + 255) / 256;                // 6250 conv blocks

    hipMemsetAsync(deg, 0, (size_t)(nNodes + 4) * sizeof(int), stream);
    convbucket_kernel<<<nbB + nbC, 256, 0, stream>>>(feat, W1, W2, tgt, nbr, vals,
                                                     featbf, Wbf, deg, edata, ovf, ovf_cnt,
                                                     nQuads, E, nbB);

    int nTiles = (nNodes + 15) / 16;                  // 3125 blocks, 1 tile each
    gathergemm_kernel<<<nTiles, 256, 0, stream>>>(featbf, edata, deg, ovf, ovf_cnt,
                                                  Wbf, b1, b2, out, nNodes);
}

// Round 4
// 178.645 us; speedup vs baseline: 1.0701x; 1.0174x over previous
//
#include <hip/hip_runtime.h>

#define D 128
#define CAP 32
#define EPT 2          // edges per thread in bucket blocks (low => high TLP for atomics)
#define NEG_SLOPE 0.01f

typedef float v4f __attribute__((ext_vector_type(4)));
typedef short short8 __attribute__((ext_vector_type(8)));

static __device__ __forceinline__ short f2bf(float f) {
    unsigned u = __float_as_uint(f);
    unsigned r = (u + 0x7fffu + ((u >> 16) & 1u)) >> 16;   // round-nearest-even
    return (short)r;
}
static __device__ __forceinline__ float bflo(unsigned u) { return __uint_as_float(u << 16); }
static __device__ __forceinline__ float bfhi(unsigned u) { return __uint_as_float(u & 0xffff0000u); }
static __device__ __forceinline__ unsigned packbf(float x, float y) {
    return (unsigned)(unsigned short)f2bf(x) | ((unsigned)(unsigned short)f2bf(y) << 16);
}

// -------- fused, block-specialized: bucket blocks + conv blocks ------------
// blocks [0, nbB)      : bucket fill, EPT edges/thread, packed 4-B entries
// blocks [nbB, ...)    : fp32->bf16 conversion stream (features + W), float4-wide
__global__ __launch_bounds__(256) void convbucket_kernel(const float* __restrict__ feat,
                                                         const float* __restrict__ W1,
                                                         const float* __restrict__ W2,
                                                         const int* __restrict__ tgt,
                                                         const int* __restrict__ nbr,
                                                         const float* __restrict__ vals,
                                                         unsigned* __restrict__ featbf,
                                                         short* __restrict__ Wbf,
                                                         int* __restrict__ deg,
                                                         unsigned* __restrict__ edata,
                                                         int4* __restrict__ ovf,
                                                         int* __restrict__ ovf_cnt,
                                                         int nQuads, int E, int nbB) {
    if ((int)blockIdx.x < nbB) {
        // ---- bucket specialist: entry = (nbr<<16) | bf16(val) ----
        int base = (blockIdx.x * 256 + threadIdx.x) * EPT;
#pragma unroll
        for (int k = 0; k < EPT; k++) {
            int e = base + k;
            if (e < E) {
                int   t = __builtin_nontemporal_load(&tgt[e]);
                int   n = __builtin_nontemporal_load(&nbr[e]);
                float v = __builtin_nontemporal_load(&vals[e]);
                int slot = atomicAdd(&deg[t], 1);
                if (slot < CAP) {
                    unsigned ent = ((unsigned)n << 16) |
                                   (unsigned)(unsigned short)f2bf(v);
                    edata[((unsigned)t << 5) + slot] = ent;
                } else {
                    int o = atomicAdd(ovf_cnt, 1);
                    int4 ov;
                    ov.x = t;
                    ov.y = n;
                    ov.z = __float_as_int(v);
                    ov.w = 0;
                    ovf[o] = ov;
                }
            }
        }
    } else {
        // ---- conv specialist: float4 in, 2x packed bf16 out ----
        int i = (blockIdx.x - nbB) * 256 + threadIdx.x;
        if (i < nQuads) {
            v4f f = __builtin_nontemporal_load((const v4f*)feat + i);
            uint2 p;
            p.x = packbf(f.x, f.y);
            p.y = packbf(f.z, f.w);
            ((uint2*)featbf)[i] = p;
        }
        if (i < D * D) {
            Wbf[i]         = f2bf(W1[i]);
            Wbf[D * D + i] = f2bf(W2[i]);
        }
    }
}

// -------- fused gather + dual-GEMM + bias + leaky relu ---------------------
// One BLOCK = one 16-node MFMA tile, 4 waves cooperating:
//   phase 1: each wave gathers 4 nodes, 16 row-loads in flight per node
//            (Poisson(12.5) degrees => 87% of nodes need ONE latency batch),
//            into a block-shared XOR-swizzled LDS tile.
//   phase 2: each wave computes 2 of the 8 output column-blocks (16 MFMAs),
//            A from LDS, W straight from global (64 KB, L1/L2-hot).
__global__ __launch_bounds__(256) void gathergemm_kernel(const unsigned* __restrict__ featbf,
                                                         const unsigned* __restrict__ edata,
                                                         const int* __restrict__ deg,
                                                         const int4* __restrict__ ovf,
                                                         const int* __restrict__ ovf_cnt,
                                                         const short* __restrict__ Wbf,
                                                         const float* __restrict__ b1,
                                                         const float* __restrict__ b2,
                                                         float* __restrict__ out,
                                                         int nNodes) {
    // [mat][16 rows * 64 dwords] = 8 KB (block-shared tile)
    __shared__ __align__(16) unsigned sX[2][1024];

    int tid  = threadIdx.x;
    int lane = tid & 63;
    int w    = tid >> 6;
    int m0   = blockIdx.x * 16;
    if (m0 >= nNodes) return;   // uniform across block

    int mrow = lane & 15;   // A: m index / B(W): n index / D: col index
    int quad = lane >> 4;   // A/B: k-group    / D: row-group

    // ---- phase 1: this wave gathers nodes m0 + 4w .. m0 + 4w+3 ----
    for (int k = 0; k < 4; k++) {
        int n    = w * 4 + k;
        int node = m0 + n;
        int d    = (node < nNodes) ? deg[node] : 0;
        int dd   = d < CAP ? d : CAP;

        unsigned uf = featbf[(long)min(node, nNodes - 1) * (D / 2) + lane];  // own row, issued early

        float ax[4] = {0.f, 0.f, 0.f, 0.f};
        float ay[4] = {0.f, 0.f, 0.f, 0.f};

        {
            const unsigned* ep = edata + ((unsigned)node << 5);
            int dm1 = dd - 1;
            // uniform loop: 16 independent row loads in flight per batch.
            for (int j = 0; j < dd; j += 16) {
                unsigned p[16], u[16];
#pragma unroll
                for (int t = 0; t < 16; t++) p[t] = ep[min(j + t, dm1)];
#pragma unroll
                for (int t = 0; t < 16; t++)
                    u[t] = featbf[(long)(p[t] >> 16) * (D / 2) + lane];
                float v[16];
#pragma unroll
                for (int t = 0; t < 16; t++) v[t] = (j + t < dd) ? bflo(p[t]) : 0.0f;
#pragma unroll
                for (int t = 0; t < 16; t++) {
                    ax[t & 3] += bflo(u[t]) * v[t];
                    ay[t & 3] += bfhi(u[t]) * v[t];
                }
            }
        }

        if (d > CAP) {
            // overflow edges live in the compact list (L2-hot, tiny)
            int cnt = *ovf_cnt;
            for (int basek = 0; basek < cnt; basek += 64) {
                int kk = basek + lane;
                int t  = (kk < cnt) ? ovf[kk].x : -1;
                unsigned long long m = __ballot(t == node);
                while (m) {
                    int b = __ffsll((long long)m) - 1;
                    m &= m - 1;
                    int4  ov = ovf[basek + b];
                    float v  = __int_as_float(ov.z);
                    unsigned u = featbf[(long)ov.y * (D / 2) + lane];
                    ax[0] += bflo(u) * v;
                    ay[0] += bfhi(u) * v;
                }
            }
        }

        float accx = (ax[0] + ax[1]) + (ax[2] + ax[3]);
        float accy = (ay[0] + ay[1]) + (ay[2] + ay[3]);
        float fx = bflo(uf), fy = bfhi(uf);
        // XOR-swizzled store: chunk c (=lane>>2) of row n lands at c^n.
        int idx = n * 64 + (((lane >> 2) ^ n) << 2) + (lane & 3);
        sX[0][idx] = packbf(fx + accx, fy + accy);
        sX[1][idx] = packbf(fx * accx, fy * accy);
    }

    __syncthreads();

    // ---- phase 2: this wave computes output col-blocks ot = 2w, 2w+1 ----
    int ot0 = w * 2;
    float bias[2];
#pragma unroll
    for (int j = 0; j < 2; j++) {
        int o = (ot0 + j) * 16 + mrow;
        bias[j] = b1[o] + b2[o];
    }

    v4f acc[2];
#pragma unroll
    for (int j = 0; j < 2; j++) acc[j] = (v4f)(0.0f);

#pragma unroll
    for (int s = 0; s < 4; s++) {
        int ck = s * 4 + quad;          // original chunk id wanted
        int pp = ck ^ mrow;             // swizzled position
        short8 a1 = *(const short8*)(&sX[0][mrow * 64 + pp * 4]);
        short8 a2 = *(const short8*)(&sX[1][mrow * 64 + pp * 4]);
        const short* wp = Wbf + ck * 8;
#pragma unroll
        for (int j = 0; j < 2; j++) {
            int row = (ot0 + j) * 16 + mrow;
            short8 w1 = *(const short8*)(wp + row * D);
            short8 w2 = *(const short8*)(wp + D * D + row * D);
            acc[j] = __builtin_amdgcn_mfma_f32_16x16x32_bf16(a1, w1, acc[j], 0, 0, 0);
            acc[j] = __builtin_amdgcn_mfma_f32_16x16x32_bf16(a2, w2, acc[j], 0, 0, 0);
        }
    }

#pragma unroll
    for (int j = 0; j < 2; j++) {
        int o = (ot0 + j) * 16 + mrow;
#pragma unroll
        for (int r = 0; r < 4; r++) {
            int node = m0 + quad * 4 + r;
            if (node < nNodes) {
                float v = acc[j][r] + bias[j];
                v = (v >= 0.0f) ? v : NEG_SLOPE * v;
                __builtin_nontemporal_store(v, &out[(long)node * D + o]);
            }
        }
    }
}

extern "C" void kernel_launch(void* const* d_in, const int* in_sizes, int n_in,
                              void* d_out, int out_size, void* d_ws, size_t ws_size,
                              hipStream_t stream) {
    const float* feat = (const float*)d_in[0];
    const int*   tgt  = (const int*)d_in[1];
    const int*   nbr  = (const int*)d_in[2];
    const float* vals = (const float*)d_in[3];
    const float* W1   = (const float*)d_in[4];
    const float* b1   = (const float*)d_in[5];
    const float* W2   = (const float*)d_in[6];
    const float* b2   = (const float*)d_in[7];
    float*       out  = (float*)d_out;

    int E      = in_sizes[1];
    int nNodes = out_size / D;

    // ---- workspace layout ----
    int*      deg     = (int*)d_ws;                             // N (+4 incl ovf_cnt)
    int*      ovf_cnt = deg + nNodes;                           // 1 (inside memset range)
    int4*     ovf     = (int4*)(deg + nNodes + 4);              // E entries (16B-aligned)
    unsigned* edata   = (unsigned*)(ovf + E);                   // N*CAP u32
    short*    Wbf     = (short*)(edata + (long)nNodes * CAP);   // 2*D*D
    unsigned* featbf  = (unsigned*)(Wbf + 2 * D * D);           // N*D/2

    int nQuads = nNodes * (D / 4);
    int nbB    = (E + 256 * EPT - 1) / (256 * EPT);   // 1221 bucket blocks
    int nbC    = (nQuads + 255) / 256;                // 6250 conv blocks

    hipMemsetAsync(deg, 0, (size_t)(nNodes + 4) * sizeof(int), stream);
    convbucket_kernel<<<nbB + nbC, 256, 0, stream>>>(feat, W1, W2, tgt, nbr, vals,
                                                     featbf, Wbf, deg, edata, ovf, ovf_cnt,
                                                     nQuads, E, nbB);

    int nTiles = (nNodes + 15) / 16;                  // 3125 blocks, 1 tile each
    gathergemm_kernel<<<nTiles, 256, 0, stream>>>(featbf, edata, deg, ovf, ovf_cnt,
                                                  Wbf, b1, b2, out, nNodes);
}